// Round 10
// baseline (191.837 us; speedup 1.0000x reference)
//
#include <hip/hip_runtime.h>
#include <hip/hip_bf16.h>

typedef __attribute__((ext_vector_type(8))) short bf16x8;
typedef __attribute__((ext_vector_type(4))) float f32x4;

#define F_DIM 128
#define N_DIM 20000
#define M_DIM 128
#define NW 32                 // n per tile (= exactly one 128B line per f-row)
#define TILES_PER_B 625       // 20000/32
#define NT 8                  // tiles per block
#define GRID 1250             // 1250*8 = 10000 tiles
#define BUF_STRIDE 16384      // one bf16 buf: 2 mats * 32nn * 128f * 2B
#define MAT_STRIDE 8192

static __device__ inline unsigned short f2bf(float x) {
    union { float f; unsigned u; } v; v.f = x;
    unsigned r = v.u + 0x7fffu + ((v.u >> 16) & 1u);   // RNE
    return (unsigned short)(r >> 16);
}

static __device__ inline unsigned cvt_pk_bf16(float lo, float hi) {
    unsigned r;
    asm("v_cvt_pk_bf16_f32 %0, %1, %2" : "=v"(r) : "v"(lo), "v"(hi));
    return r;
}

// ---------------------------------------------------------------------------
// Kernel 1: fold resize into projections; bf16 in MFMA fragment order.
// ---------------------------------------------------------------------------
__global__ __launch_bounds__(256) void precompute_mats(
    const float* __restrict__ W_rs,   // (128, 384)
    const float* __restrict__ W_e2m,  // (128, 128)
    const float* __restrict__ W_n2m,  // (128, 128)
    unsigned short* __restrict__ wsA,
    unsigned short* __restrict__ wsB)
{
    int idx = blockIdx.x * 256 + threadIdx.x;   // 0..16383
    int k = idx >> 7;
    int f = idx & 127;
    float a = 0.f, b = 0.f;
    for (int m = 0; m < 128; ++m) {
        a += W_rs[k * 384 + m]       * W_e2m[m * 128 + f];
        b += W_rs[k * 384 + 128 + m] * W_n2m[m * 128 + f];
    }
    int mt = k >> 4, row = k & 15;
    int c = f >> 5, kk = f & 31;
    int lane = ((kk >> 3) << 4) | row;
    int j = kk & 7;
    int off = ((mt * 4 + c) * 64 + lane) * 8 + j;
    wsA[off] = f2bf(a);
    wsB[off] = f2bf(b);
}

// ---------------------------------------------------------------------------
// Kernel 2: per-(b,k) bias.
// ---------------------------------------------------------------------------
__global__ __launch_bounds__(128) void precompute_bias(
    const float* __restrict__ W_rs,
    const float* __restrict__ h_v,
    const float* __restrict__ b_e2m,
    const float* __restrict__ b_n2m,
    const float* __restrict__ b_rs,
    const float* __restrict__ W_n2m,
    float* __restrict__ bias)
{
    __shared__ float nv_s[128];
    int b = blockIdx.x;
    int t = threadIdx.x;
    {
        float nv = b_n2m[t];
        for (int f = 0; f < 128; ++f)
            nv += h_v[b * 128 + f] * W_n2m[t * 128 + f];
        nv_s[t] = nv;
    }
    __syncthreads();
    {
        float acc = b_rs[t];
        for (int m = 0; m < 128; ++m) {
            acc += W_rs[t * 384 + m]       * b_e2m[m];
            acc += W_rs[t * 384 + 128 + m] * b_n2m[m];
            acc += W_rs[t * 384 + 256 + m] * nv_s[m];
        }
        bias[b * 128 + t] = acc;
    }
}

// ---------------------------------------------------------------------------
// Kernel 3: streaming GEMM, ONE barrier per iteration.
// Per iter: reg-load tile t+1 (8x dwordx4, 8 full 128B lines per wave-instr)
//   -> compute(t) from bf16 buf[t&1] (pure LDS+MFMA; loads stay in flight)
//   -> bias+stores(t) -> cvt_pk + swizzled ds_write -> buf[(t+1)&1]
//   -> __syncthreads().
// Buffer parity proves 1 barrier/iter is sufficient: reads of buf[t&1]
// precede barrier(t); buf[t&1] is rewritten only after barrier(t).
// LDS 32KB (no f32 stage). No manual vmcnt (compiler emits exact counts;
// stores stay outstanding past the cvt wait).
// ---------------------------------------------------------------------------
__global__ void msg_main(
    const float* __restrict__ e_wv,
    const float* __restrict__ h_w,
    const unsigned short* __restrict__ wsA,
    const unsigned short* __restrict__ wsB,
    const float* __restrict__ bias,
    float* __restrict__ out)
{
    __shared__ __align__(16) unsigned char smem[2 * BUF_STRIDE];   // 32 KB

    int tid = threadIdx.x;
    int w   = tid >> 6;
    int l   = tid & 63;
    unsigned base = (unsigned)blockIdx.x * NT;

    // ---- preload weight fragments (loop-invariant, 64 VGPR)
    const bf16x8* Af = (const bf16x8*)wsA;
    const bf16x8* Bf = (const bf16x8*)wsB;
    bf16x8 A0[4], A1[4], B0[4], B1[4];
#pragma unroll
    for (int c = 0; c < 4; ++c) {
        A0[c] = Af[((2 * w + 0) * 4 + c) * 64 + l];
        A1[c] = Af[((2 * w + 1) * 4 + c) * 64 + l];
        B0[c] = Bf[((2 * w + 0) * 4 + c) * 64 + l];
        B1[c] = Bf[((2 * w + 1) * 4 + c) * 64 + l];
    }

    int r = l >> 3;   // f-row within group of 8 (stride 2)
    int q = l & 7;    // 16B slot within the 128B row (4 n)

    // stage regs: [mat][j][par], j = f-group, par = even/odd f
    f32x4 ve[2][2], vw[2][2];
    auto load_tile = [&](unsigned tau) {
        unsigned bb = tau / TILES_PER_B;
        unsigned n0 = (tau - bb * TILES_PER_B) * NW;
        const float* eb = e_wv + (size_t)bb * (F_DIM * (size_t)N_DIM) + n0 + 4 * q;
        const float* wb = h_w  + (size_t)bb * (F_DIM * (size_t)N_DIM) + n0 + 4 * q;
#pragma unroll
        for (int j = 0; j < 2; ++j)
#pragma unroll
            for (int par = 0; par < 2; ++par) {
                int f = w * 32 + j * 16 + 2 * r + par;
                ve[j][par] = *(const f32x4*)(eb + (size_t)f * N_DIM);
                vw[j][par] = *(const f32x4*)(wb + (size_t)f * N_DIM);
            }
    };

    auto cvt_write = [&](unsigned bufsel) {
        unsigned char* be = smem + bufsel * BUF_STRIDE;
        unsigned char* bw = be + MAT_STRIDE;
#pragma unroll
        for (int j = 0; j < 2; ++j) {
            unsigned fp = (unsigned)(w * 16 + j * 8 + r);   // f-pair index
#pragma unroll
            for (int e = 0; e < 4; ++e) {
                unsigned nn = (unsigned)(4 * q + e);
                unsigned off = nn * 256 + ((fp * 4) ^ ((nn & 7) << 4));
                *(unsigned*)(be + off) = cvt_pk_bf16(ve[j][0][e], ve[j][1][e]);
                *(unsigned*)(bw + off) = cvt_pk_bf16(vw[j][0][e], vw[j][1][e]);
            }
        }
    };

    // ---- prologue: stage tile 0
    load_tile(base);
    cvt_write(0);
    __syncthreads();

    int ln = l & 15, g = l >> 4;
    unsigned rbase = (unsigned)(ln * 256);
    unsigned rx = (unsigned)((ln & 7) << 4);

#pragma unroll 1
    for (int t = 0; t < NT; ++t) {
        unsigned tau = base + t;
        unsigned bb = tau / TILES_PER_B;
        unsigned n0 = (tau - bb * TILES_PER_B) * NW;

        // bias first (oldest in VMEM queue -> its wait leaves stage loads out)
        const float* bp = bias + bb * 128;
        f32x4 bv0 = *(const f32x4*)(bp + (2 * w + 0) * 16 + g * 4);
        f32x4 bv1 = *(const f32x4*)(bp + (2 * w + 1) * 16 + g * 4);

        // issue next tile's reg-loads; pin issue before compute
        if (t + 1 < NT) load_tile(base + t + 1);
        __builtin_amdgcn_sched_barrier(0);

        // compute(t) from buf[t&1] — pure LDS + MFMA
        const unsigned char* bufp = smem + (unsigned)(t & 1) * BUF_STRIDE;
        f32x4 acc[2][2];
#pragma unroll
        for (int mtL = 0; mtL < 2; ++mtL)
#pragma unroll
            for (int ns = 0; ns < 2; ++ns) acc[mtL][ns] = (f32x4)(0.f);
#pragma unroll
        for (int c = 0; c < 4; ++c) {
            unsigned fbyte = (unsigned)((c * 32 + g * 8) * 2) ^ rx;
#pragma unroll
            for (int ns = 0; ns < 2; ++ns) {
                bf16x8 xe = *(const bf16x8*)(bufp + ns * 4096 + rbase + fbyte);
                bf16x8 xw = *(const bf16x8*)(bufp + MAT_STRIDE + ns * 4096 + rbase + fbyte);
                acc[0][ns] = __builtin_amdgcn_mfma_f32_16x16x32_bf16(A0[c], xe, acc[0][ns], 0, 0, 0);
                acc[0][ns] = __builtin_amdgcn_mfma_f32_16x16x32_bf16(B0[c], xw, acc[0][ns], 0, 0, 0);
                acc[1][ns] = __builtin_amdgcn_mfma_f32_16x16x32_bf16(A1[c], xe, acc[1][ns], 0, 0, 0);
                acc[1][ns] = __builtin_amdgcn_mfma_f32_16x16x32_bf16(B1[c], xw, acc[1][ns], 0, 0, 0);
            }
        }

        // stores(t): plain dwords; two 64B halves of each 128B line back-to-back
        float* O = out + (size_t)bb * (M_DIM * (size_t)N_DIM) + n0 + ln;
#pragma unroll
        for (int mtL = 0; mtL < 2; ++mtL) {
            f32x4 bv = mtL ? bv1 : bv0;
            int mt = 2 * w + mtL;
#pragma unroll
            for (int ns = 0; ns < 2; ++ns)
#pragma unroll
                for (int rr = 0; rr < 4; ++rr)
                    O[(size_t)(mt * 16 + g * 4 + rr) * N_DIM + ns * 16] =
                        acc[mtL][ns][rr] + bv[rr];
        }

        // stage t+1 into the other buffer (compiler waits exactly on the
        // stage loads, leaving the 16 stores outstanding)
        if (t + 1 < NT) cvt_write((unsigned)((t + 1) & 1));
        __syncthreads();
    }
}

extern "C" void kernel_launch(void* const* d_in, const int* in_sizes, int n_in,
                              void* d_out, int out_size, void* d_ws, size_t ws_size,
                              hipStream_t stream) {
    const float* h_w   = (const float*)d_in[0];
    const float* h_v   = (const float*)d_in[1];
    const float* e_wv  = (const float*)d_in[2];
    const float* W_e2m = (const float*)d_in[3];
    const float* b_e2m = (const float*)d_in[4];
    const float* W_n2m = (const float*)d_in[5];
    const float* b_n2m = (const float*)d_in[6];
    const float* W_rs  = (const float*)d_in[7];
    const float* b_rs  = (const float*)d_in[8];
    float* out = (float*)d_out;

    unsigned short* wsA = (unsigned short*)d_ws;                     // 32 KB
    unsigned short* wsB = wsA + 128 * 128;                           // 32 KB
    float* bias = (float*)((char*)d_ws + 65536);                     // 8 KB

    precompute_mats<<<64, 256, 0, stream>>>(W_rs, W_e2m, W_n2m, wsA, wsB);
    precompute_bias<<<16, 128, 0, stream>>>(W_rs, h_v, b_e2m, b_n2m, b_rs, W_n2m, bias);
    msg_main<<<GRID, 256, 0, stream>>>(e_wv, h_w, wsA, wsB, bias, out);
}

// Round 12
// 136.540 us; speedup vs baseline: 1.4050x; 1.4050x over previous
//
#include <hip/hip_runtime.h>
#include <hip/hip_bf16.h>

typedef __attribute__((ext_vector_type(8))) short bf16x8;
typedef __attribute__((ext_vector_type(4))) float f32x4;

#define F_DIM 128
#define N_DIM 20000
#define M_DIM 128
#define NW 32                 // n per tile
#define TILES_PER_B 625       // 20000/32
#define NT 20                 // tiles per block
#define GRID 500              // 500*20 = 10000 tiles
#define F32_TILE 32768        // per-tile f32 stage: 2 mats * 128f * 32n * 4B
#define F32_MAT 16384
#define BF16_OFF 65536        // after 2 f32 buffers
#define BF16_MAT 8192

#define AS1 __attribute__((address_space(1)))
#define AS3 __attribute__((address_space(3)))

static __device__ inline unsigned short f2bf(float x) {
    union { float f; unsigned u; } v; v.f = x;
    unsigned r = v.u + 0x7fffu + ((v.u >> 16) & 1u);   // RNE
    return (unsigned short)(r >> 16);
}

static __device__ inline unsigned cvt_pk_bf16(float lo, float hi) {
    unsigned r;
    asm("v_cvt_pk_bf16_f32 %0, %1, %2" : "=v"(r) : "v"(lo), "v"(hi));
    return r;
}

// ---------------------------------------------------------------------------
// Kernel 1: fold resize into projections; bf16 in MFMA fragment order.
// ---------------------------------------------------------------------------
__global__ __launch_bounds__(256) void precompute_mats(
    const float* __restrict__ W_rs,   // (128, 384)
    const float* __restrict__ W_e2m,  // (128, 128)
    const float* __restrict__ W_n2m,  // (128, 128)
    unsigned short* __restrict__ wsA,
    unsigned short* __restrict__ wsB)
{
    int idx = blockIdx.x * 256 + threadIdx.x;   // 0..16383
    int k = idx >> 7;
    int f = idx & 127;
    float a = 0.f, b = 0.f;
    for (int m = 0; m < 128; ++m) {
        a += W_rs[k * 384 + m]       * W_e2m[m * 128 + f];
        b += W_rs[k * 384 + 128 + m] * W_n2m[m * 128 + f];
    }
    int mt = k >> 4, row = k & 15;
    int c = f >> 5, kk = f & 31;
    int lane = ((kk >> 3) << 4) | row;
    int j = kk & 7;
    int off = ((mt * 4 + c) * 64 + lane) * 8 + j;
    wsA[off] = f2bf(a);
    wsB[off] = f2bf(b);
}

// ---------------------------------------------------------------------------
// Kernel 2: per-(b,k) bias.
// ---------------------------------------------------------------------------
__global__ __launch_bounds__(128) void precompute_bias(
    const float* __restrict__ W_rs,
    const float* __restrict__ h_v,
    const float* __restrict__ b_e2m,
    const float* __restrict__ b_n2m,
    const float* __restrict__ b_rs,
    const float* __restrict__ W_n2m,
    float* __restrict__ bias)
{
    __shared__ float nv_s[128];
    int b = blockIdx.x;
    int t = threadIdx.x;
    {
        float nv = b_n2m[t];
        for (int f = 0; f < 128; ++f)
            nv += h_v[b * 128 + f] * W_n2m[t * 128 + f];
        nv_s[t] = nv;
    }
    __syncthreads();
    {
        float acc = b_rs[t];
        for (int m = 0; m < 128; ++m) {
            acc += W_rs[t * 384 + m]       * b_e2m[m];
            acc += W_rs[t * 384 + 128 + m] * b_n2m[m];
            acc += W_rs[t * 384 + 256 + m] * nv_s[m];
        }
        bias[b * 128 + t] = acc;
    }
}

// ---------------------------------------------------------------------------
// Kernel 3: persistent pipelined streaming GEMM, OPERAND-SWAPPED MFMA.
// mfma(X_frag, W_frag, acc): A/B fragment layouts are index-identical, so the
// swap transposes D in-register: lane holds 4 CONSECUTIVE n at fixed
// k = mt*16 + (lane&15) -> epilogue = 4 global_store_dwordx4 per wave
// (was 16 scalar dwords). Bias is per-lane scalar, prefetched 1 iter ahead so
// its compiler-inserted wait never forces store retirement.
// Steady queue at wait: [DMA(t+1) 8][stores(t-1) 4][bias(t+1) 2][DMA(t+2) 8]
//   -> vmcnt(14); t==0 -> vmcnt(10); prologue vmcnt(8).
// ---------------------------------------------------------------------------
__global__ __launch_bounds__(256, 2) void msg_main(
    const float* __restrict__ e_wv,
    const float* __restrict__ h_w,
    const unsigned short* __restrict__ wsA,
    const unsigned short* __restrict__ wsB,
    const float* __restrict__ bias,
    float* __restrict__ out)
{
    __shared__ __align__(16) unsigned char smem[81920];   // 2x32KB f32 + 16KB bf16

    int tid = threadIdx.x;
    int w   = tid >> 6;
    int l   = tid & 63;
    unsigned base = (unsigned)blockIdx.x * NT;

    // ---- preload weight fragments (loop-invariant, 64 VGPR)
    const bf16x8* Af = (const bf16x8*)wsA;
    const bf16x8* Bf = (const bf16x8*)wsB;
    bf16x8 A0[4], A1[4], B0[4], B1[4];
#pragma unroll
    for (int c = 0; c < 4; ++c) {
        A0[c] = Af[((2 * w + 0) * 4 + c) * 64 + l];
        A1[c] = Af[((2 * w + 1) * 4 + c) * 64 + l];
        B0[c] = Bf[((2 * w + 0) * 4 + c) * 64 + l];
        B1[c] = Bf[((2 * w + 1) * 4 + c) * 64 + l];
    }

    int ln = l & 15, g = l >> 4;
    int fl = l >> 3, p = l & 7;

    auto issue_dma = [&](unsigned tau, unsigned bufsel) {
        unsigned bb = tau / TILES_PER_B;
        unsigned n0 = (tau - bb * TILES_PER_B) * NW;
        const float* eb = e_wv + (size_t)bb * (F_DIM * (size_t)N_DIM) + n0;
        const float* wp = h_w  + (size_t)bb * (F_DIM * (size_t)N_DIM) + n0;
        unsigned char* buf = smem + bufsel * F32_TILE;
#pragma unroll
        for (int i = 0; i < 4; ++i) {
            int fb = i * 32 + w * 8;
            int f  = fb + fl;
            int gx = (f ^ (f >> 3)) & 7;
            int col = (p ^ gx) << 2;
            __builtin_amdgcn_global_load_lds(
                (const AS1 unsigned*)(eb + (size_t)f * N_DIM + col),
                (AS3 unsigned*)(buf + fb * 128), 16, 0, 0);
            __builtin_amdgcn_global_load_lds(
                (const AS1 unsigned*)(wp + (size_t)f * N_DIM + col),
                (AS3 unsigned*)(buf + F32_MAT + fb * 128), 16, 0, 0);
        }
    };

    // lane-uniform dummy DMAs (L2-hit): keep vmcnt counts uniform at tail.
    auto issue_dma_dummy = [&](unsigned bufsel) {
        unsigned char* buf = smem + bufsel * F32_TILE;
#pragma unroll
        for (int i = 0; i < 4; ++i) {
            int fb = i * 32 + w * 8;
            __builtin_amdgcn_global_load_lds(
                (const AS1 unsigned*)e_wv,
                (AS3 unsigned*)(buf + fb * 128), 16, 0, 0);
            __builtin_amdgcn_global_load_lds(
                (const AS1 unsigned*)h_w,
                (AS3 unsigned*)(buf + F32_MAT + fb * 128), 16, 0, 0);
        }
    };

    auto transform = [&](unsigned bufsel) {
        const unsigned char* fsrc = smem + bufsel * F32_TILE + (tid >> 7) * F32_MAT;
        unsigned char* bdst = smem + BF16_OFF + (tid >> 7) * BF16_MAT;
        int u = tid & 127;
        int fp = u >> 1, half = u & 1;
        int f0 = 2 * fp, f1 = 2 * fp + 1;
        int g0 = (f0 ^ (f0 >> 3)) & 7, g1 = (f1 ^ (f1 >> 3)) & 7;
#pragma unroll
        for (int j = 0; j < 4; ++j) {
            int q = half * 4 + j;
            f32x4 a = *(const f32x4*)(fsrc + f0 * 128 + ((q ^ g0) << 4));
            f32x4 c = *(const f32x4*)(fsrc + f1 * 128 + ((q ^ g1) << 4));
#pragma unroll
            for (int e = 0; e < 4; ++e) {
                int n = q * 4 + e;
                unsigned pk = cvt_pk_bf16(a[e], c[e]);   // lo=f0, hi=f1
                unsigned off = (unsigned)(n * 256) +
                               (((unsigned)(fp * 4)) ^ ((unsigned)((n & 7) << 4)));
                *(unsigned*)(bdst + off) = pk;
            }
        }
    };

    // ---- prologue: bias(0) + DMA tiles 0,1; transform tile 0
    float bvc0, bvc1;
    {
        unsigned bb0 = base / TILES_PER_B;
        bvc0 = bias[bb0 * 128 + (2 * w + 0) * 16 + ln];
        bvc1 = bias[bb0 * 128 + (2 * w + 1) * 16 + ln];
    }
    issue_dma(base + 0, 0);
    issue_dma(base + 1, 1);
    asm volatile("s_waitcnt vmcnt(8)" ::: "memory");   // DMA(0) done
    __builtin_amdgcn_s_barrier();
    transform(0);
    asm volatile("s_waitcnt lgkmcnt(0)" ::: "memory");
    __builtin_amdgcn_s_barrier();

    unsigned rbase = (unsigned)(ln * 256);
    unsigned rx = (unsigned)((ln & 7) << 4);
    const unsigned char* ldse = smem + BF16_OFF;
    const unsigned char* ldsw = smem + BF16_OFF + BF16_MAT;

#pragma unroll 1
    for (int t = 0; t < NT; ++t) {
        unsigned tau = base + t;
        unsigned bb = tau / TILES_PER_B;
        unsigned n0 = (tau - bb * TILES_PER_B) * NW;

        // bias prefetch for t+1 (BEFORE DMA(t+2) in the queue)
        float bvn0, bvn1;
        {
            unsigned tn = base + (unsigned)(t + 1 < NT ? t + 1 : t);
            unsigned bbn = tn / TILES_PER_B;
            bvn0 = bias[bbn * 128 + (2 * w + 0) * 16 + ln];
            bvn1 = bias[bbn * 128 + (2 * w + 1) * 16 + ln];
        }

        // issue DMA for tile t+2 (dummy on last two iters)
        if (t < NT - 2) issue_dma(base + t + 2, (unsigned)(t & 1));
        else            issue_dma_dummy((unsigned)(t & 1));

        // compute(t), operand-swapped: acc = mfma(X, W, acc)
        f32x4 acc[2][2];
#pragma unroll
        for (int mtL = 0; mtL < 2; ++mtL)
#pragma unroll
            for (int ns = 0; ns < 2; ++ns) acc[mtL][ns] = (f32x4)(0.f);
#pragma unroll
        for (int c = 0; c < 4; ++c) {
            unsigned fbyte = (unsigned)((c * 32 + g * 8) * 2) ^ rx;
#pragma unroll
            for (int ns = 0; ns < 2; ++ns) {
                bf16x8 xe = *(const bf16x8*)(ldse + ns * 4096 + rbase + fbyte);
                bf16x8 xw = *(const bf16x8*)(ldsw + ns * 4096 + rbase + fbyte);
                acc[0][ns] = __builtin_amdgcn_mfma_f32_16x16x32_bf16(xe, A0[c], acc[0][ns], 0, 0, 0);
                acc[0][ns] = __builtin_amdgcn_mfma_f32_16x16x32_bf16(xw, B0[c], acc[0][ns], 0, 0, 0);
                acc[1][ns] = __builtin_amdgcn_mfma_f32_16x16x32_bf16(xe, A1[c], acc[1][ns], 0, 0, 0);
                acc[1][ns] = __builtin_amdgcn_mfma_f32_16x16x32_bf16(xw, B1[c], acc[1][ns], 0, 0, 0);
            }
        }

        // counted wait: DMA(t+1) retired <=> outstanding <= 14
        // (queue: stores(t-1) 4 + bias(t+1) 2 + DMA(t+2) 8; t==0: 10)
        if (t == 0) { asm volatile("s_waitcnt vmcnt(10)" ::: "memory"); }
        else        { asm volatile("s_waitcnt vmcnt(14)" ::: "memory"); }
        asm volatile("s_waitcnt lgkmcnt(0)" ::: "memory");
        __builtin_amdgcn_s_barrier();

        if (t < NT - 1) transform((unsigned)((t + 1) & 1));
        asm volatile("s_waitcnt lgkmcnt(0)" ::: "memory");
        __builtin_amdgcn_s_barrier();

        // store(t): D is transposed -> lane owns 4 consecutive n at fixed k.
        // 4 dwordx4 stores per wave (16 rows x 64B each instr).
        float* O = out + (size_t)bb * (M_DIM * (size_t)N_DIM) + n0;
#pragma unroll
        for (int mtL = 0; mtL < 2; ++mtL) {
            float bv = mtL ? bvc1 : bvc0;
            int k = (2 * w + mtL) * 16 + ln;
#pragma unroll
            for (int ns = 0; ns < 2; ++ns) {
                f32x4 v = acc[mtL][ns];
                v[0] += bv; v[1] += bv; v[2] += bv; v[3] += bv;
                *(f32x4*)(O + (size_t)k * N_DIM + ns * 16 + g * 4) = v;
            }
        }

        bvc0 = bvn0; bvc1 = bvn1;
    }

    // drain outstanding DMAs before endpgm (LDS reuse hazard)
    asm volatile("s_waitcnt vmcnt(0)" ::: "memory");
}

extern "C" void kernel_launch(void* const* d_in, const int* in_sizes, int n_in,
                              void* d_out, int out_size, void* d_ws, size_t ws_size,
                              hipStream_t stream) {
    const float* h_w   = (const float*)d_in[0];
    const float* h_v   = (const float*)d_in[1];
    const float* e_wv  = (const float*)d_in[2];
    const float* W_e2m = (const float*)d_in[3];
    const float* b_e2m = (const float*)d_in[4];
    const float* W_n2m = (const float*)d_in[5];
    const float* b_n2m = (const float*)d_in[6];
    const float* W_rs  = (const float*)d_in[7];
    const float* b_rs  = (const float*)d_in[8];
    float* out = (float*)d_out;

    unsigned short* wsA = (unsigned short*)d_ws;                     // 32 KB
    unsigned short* wsB = wsA + 128 * 128;                           // 32 KB
    float* bias = (float*)((char*)d_ws + 65536);                     // 8 KB

    precompute_mats<<<64, 256, 0, stream>>>(W_rs, W_e2m, W_n2m, wsA, wsB);
    precompute_bias<<<16, 128, 0, stream>>>(W_rs, h_v, b_e2m, b_n2m, b_rs, W_n2m, bias);
    msg_main<<<GRID, 256, 0, stream>>>(e_wv, h_w, wsA, wsB, bias, out);
}